// Round 9
// baseline (612.987 us; speedup 1.0000x reference)
//
#include <hip/hip_runtime.h>
#include <cstdint>
#include <cstddef>

#define BSZ 16
#define T   8192
#define CDIM 256
#define HDIM 256
#define KW  7

constexpr int BT = BSZ * T;                  // 131072
constexpr float TAU = 2e-3f;                 // f64 recheck band for |d| (fp16 path: sigma_d ~1.5e-4, band ~13 sigma)
constexpr int RCAP = 8192;                   // recheck candidate cap (measured n ~ O(1000))

typedef __attribute__((ext_vector_type(8))) short short8;
typedef _Float16 half8 __attribute__((ext_vector_type(8)));
typedef __attribute__((ext_vector_type(4))) float f32x4;

// ---------------- workspace layout (byte offsets, all 16B-aligned) ----------------
constexpr size_t B_W1T  = 0;                         // f32 [256][7*256]  1835008 B ([h][k*256+c], recheck)
constexpr size_t B_W2T  = B_W1T + 1835008;           // f32 [256][3*256]   786432 B ([h][k*256+c])
constexpr size_t B_V    = B_W2T + 786432;            // f32 [256]
constexpr size_t B_D    = B_V + 1024;                // f32 [BT]
constexpr size_t B_ISB  = B_D + 524288;              // i32 [BT]
constexpr size_t B_SID  = B_ISB + 524288;            // i32 [BT]
constexpr size_t B_SST  = B_SID + 524288;            // i32 [BT]
constexpr size_t B_SEN  = B_SST + 524288;            // i32 [BT]
constexpr size_t B_NV   = B_SEN + 524288;            // i32 [16]
constexpr size_t B_UCT  = B_NV + 64;                 // i32 [1]
constexpr size_t B_UL   = B_UCT + 16;                // i32 [RCAP]    32768 B
constexpr size_t B_ZERO = B_UL + 32768;              // 256 B of zeros (DMA clamp target)
constexpr size_t B_W1B  = B_ZERO + 256;              // f16 DMA-linear [4][8][28][64][8]  917504 B
constexpr size_t B_W2B  = B_W1B + 917504;            // f16 DMA-linear [4][8][12][64][8]  393216 B
constexpr size_t B_H1F  = B_W2B + 393216;            // f32 [RCAP][3][256] 25165824 B (recheck h1 scratch)
constexpr size_t B_DSUM = B_H1F + 25165824;          // f64 [RCAP]          65536 B  -> ~31.8 MB total

// async global->LDS, 16B per lane; LDS dest = wave-uniform base + lane*16 (global addr per-lane)
__device__ __forceinline__ void gl_lds16(const void* g, void* l) {
    __builtin_amdgcn_global_load_lds(
        (const __attribute__((address_space(1))) unsigned int*)g,
        (__attribute__((address_space(3))) unsigned int*)l,
        16, 0, 0);
}

// f32 -> f16 RNE (hardware default round mode for v_cvt_f16_f32)
__device__ __forceinline__ unsigned short f16_rne(float f) {
    _Float16 h = (_Float16)f;
    return __builtin_bit_cast(unsigned short, h);
}

// Tiled f16 activation layout (xt and h1t): halfword index of (b, t, c) =
//   ((((b*32 + (t>>8))*8 + (c>>5))*4 + ((c>>3)&3))*256 + (t&255))*8 + (c&7)
// -> A-stage lanes (consecutive t, fixed 8-c chunk) read contiguous 16B chunks.

// ---------------- weight repack ----------------
// W1R/W2R: f32 [h][kw*256+c] for f64 recheck. W1bL/W2bL: f16 in consumption order
// [h0g(4)][cc(8)][slot=kw*4+bq][lane=h(64)][8e]  (h = h0g*64+lane, c = cc*32+bq*8+e)
__global__ void repack_kernel(const float* __restrict__ w1, const float* __restrict__ w2,
                              const float* __restrict__ w3,
                              float* __restrict__ W1R, float* __restrict__ W2R,
                              float* __restrict__ v,
                              unsigned short* __restrict__ W1bL, unsigned short* __restrict__ W2bL)
{
    int idx = blockIdx.x * blockDim.x + threadIdx.x;
    int stride = gridDim.x * blockDim.x;
    for (int i = idx; i < HDIM * 1792; i += stride) {
        int h = i / 1792, kc = i % 1792, kw = kc >> 8, c = kc & 255;
        W1R[i] = w1[(size_t)h * 1792 + c * 7 + kw];
    }
    for (int i = idx; i < HDIM * 768; i += stride) {
        int h = i / 768, kc = i % 768, kw = kc >> 8, c = kc & 255;
        W2R[i] = w2[(size_t)h * 768 + c * 3 + kw];
    }
    for (int o = idx; o < 4 * 8 * 28 * 512; o += stride) {
        int e = o & 7, lane = (o >> 3) & 63;
        int su = o >> 9;
        int slot = su % 28, rest = su / 28;
        int cc = rest & 7, h0g = rest >> 3;
        int kw = slot >> 2, bq = slot & 3;
        int h = h0g * 64 + lane;
        int c = cc * 32 + bq * 8 + e;
        W1bL[o] = f16_rne(w1[(size_t)h * 1792 + c * 7 + kw]);
    }
    for (int o = idx; o < 4 * 8 * 12 * 512; o += stride) {
        int e = o & 7, lane = (o >> 3) & 63;
        int su = o >> 9;
        int slot = su % 12, rest = su / 12;
        int cc = rest & 7, h0g = rest >> 3;
        int kw = slot >> 2, bq = slot & 3;
        int h = h0g * 64 + lane;
        int c = cc * 32 + bq * 8 + e;
        W2bL[o] = f16_rne(w2[(size_t)h * 768 + c * 3 + kw]);
    }
    if (idx < HDIM) v[idx] = w3[HDIM + idx] - w3[idx];
}

// ---------------- x -> f16 tiled layout (output-indexed, coalesced 16B writes) ----------------
__global__ __launch_bounds__(256) void xcast_kernel(const float* __restrict__ x,
                                                    unsigned short* __restrict__ xt)
{
    int j = blockIdx.x * 256 + threadIdx.x;      // 8-half chunk index, [b][grp][cc][wid][rin]
    int rin = j & 255, wid = (j >> 8) & 3, cc = (j >> 10) & 7, grp = (j >> 13) & 31, b = j >> 18;
    int t = grp * 256 + rin;
    int c0 = cc * 32 + wid * 8;
    const float* src = x + ((size_t)(b * T + t)) * 256 + c0;
    float4 a = *(const float4*)src;
    float4 bb = *(const float4*)(src + 4);
    short8 o;
    o[0] = (short)f16_rne(a.x); o[1] = (short)f16_rne(a.y);
    o[2] = (short)f16_rne(a.z); o[3] = (short)f16_rne(a.w);
    o[4] = (short)f16_rne(bb.x); o[5] = (short)f16_rne(bb.y);
    o[6] = (short)f16_rne(bb.z); o[7] = (short)f16_rne(bb.w);
    *(short8*)(xt + (size_t)j * 8) = o;
}

// ---------------- conv1: f16 MFMA; A via LDS-DMA, B direct from L1/L2 ----------------
// LDS-pipe accounting at round 8 (reads 70us + conflicts 24 + writes 11 ~= 105us
// vs MFMA 58us) showed LDS is the binding pipe. B fragments are wave-uniform and
// L1-resident (28KB/cc < 32KB L1), so B moves to the vector-memory pipe: no B8,
// no B staging; 1-kw-deep register prefetch hides L2 latency under the MFMA cluster.
// XCD swizzle: same-XCD blocks get consecutive work ids -> the 4 y-siblings of an
// xt panel share one L2 (round 8 FETCH doubled because they landed on 4 XCDs).
__device__ __forceinline__ void c1_stageA(const unsigned short* xt, const unsigned short* zerobuf,
                                          half8* Ab, int b, int t0, int cc, int lane, int wid)
{
    #pragma unroll
    for (int part = 0; part < 5; ++part) {
        int row = part * 64 + lane;
        int t = t0 + row - 3;
        const unsigned short* src = zerobuf;
        if (row < 262 && t >= 0 && t < T) {
            int grp = t >> 8, rin = t & 255;
            src = xt + ((size_t)((((b * 32 + grp) * 8 + cc) * 4 + wid) * 256 + rin)) * 8;
        }
        gl_lds16(src, &Ab[wid * 322 + part * 64]);
    }
}

__global__ __launch_bounds__(256, 3) void conv1_mfma(
    const unsigned short* __restrict__ xt,
    const unsigned short* __restrict__ WbL,
    const float* __restrict__ b1,
    const unsigned short* __restrict__ zerobuf,
    unsigned short* __restrict__ h1t)
{
    __shared__ half8 A8[4 * 322];        // [q][row], rows 0..261 valid (t = t0+row-3)  20.6 KB
    const int tid = threadIdx.x, lane = tid & 63, wid = tid >> 6;
    // XCD-aware bijective swizzle (2048 % 8 == 0): XCD k processes cids [k*256,(k+1)*256)
    const int bid = blockIdx.x;
    const int cid = (bid & 7) * 256 + (bid >> 3);
    const int xcol = cid >> 2;           // 0..511 = b*32+grp
    const int ycol = cid & 3;            // h-group (y-siblings adjacent on one XCD)
    const int b  = xcol >> 5;
    const int grp = xcol & 31;
    const int t0 = grp << 8;
    const int h0 = ycol << 6;
    const int q = lane >> 4, l15 = lane & 15;
    // per-lane B base: frag(cc,kw,j) at Wl0 + cc*14336 + kw*2048 + j*128 (halfwords)
    const unsigned short* Wl0 = WbL + (size_t)(ycol * 8) * 28 * 512
                                + (size_t)(q * 64 + l15) * 8;

    f32x4 acc[4][4] = {};

    for (int cc = 0; cc < 8; ++cc) {
        __syncthreads();                 // previous compute fully consumed A8
        c1_stageA(xt, zerobuf, A8, b, t0, cc, lane, wid);
        const unsigned short* Wl = Wl0 + (size_t)cc * 14336;
        half8 bh0[4], bh1[4];
        #pragma unroll
        for (int j = 0; j < 4; ++j) bh0[j] = *(const half8*)(Wl + j * 128);
        __syncthreads();                 // drain A DMAs (B loads fly alongside)
        #pragma unroll
        for (int kw = 0; kw < 7; ++kw) {
            half8* cur = (kw & 1) ? bh1 : bh0;
            half8* nxt = (kw & 1) ? bh0 : bh1;
            if (kw < 6) {
                #pragma unroll
                for (int j = 0; j < 4; ++j)
                    nxt[j] = *(const half8*)(Wl + (kw + 1) * 2048 + j * 128);
            }
            half8 ah[4];
            const int rbase = wid * 64 + l15 + kw;
            #pragma unroll
            for (int i = 0; i < 4; ++i) ah[i] = A8[q * 322 + rbase + i * 16];
            #pragma unroll
            for (int i = 0; i < 4; ++i)
                #pragma unroll
                for (int j = 0; j < 4; ++j)
                    acc[i][j] = __builtin_amdgcn_mfma_f32_16x16x32_f16(ah[i], cur[j], acc[i][j], 0, 0, 0);
        }
    }
    // epilogue: bias+relu, store h1 f16 in the tiled layout
    #pragma unroll
    for (int j = 0; j < 4; ++j) {
        int h = h0 + j * 16 + l15;
        float bb = b1[h];
        int hcc = h >> 5, hwid = (h >> 3) & 3, he = h & 7;
        size_t hbase = ((size_t)(((b * 32 + grp) * 8 + hcc) * 4 + hwid)) * 2048 + he;
        #pragma unroll
        for (int i = 0; i < 4; ++i) {
            int rb = wid * 64 + i * 16 + q * 4;    // rin
            #pragma unroll
            for (int r = 0; r < 4; ++r)
                h1t[hbase + (size_t)(rb + r) * 8] = f16_rne(fmaxf(acc[i][j][r] + bb, 0.f));
        }
    }
}

// ---------------- conv2: f16 MFMA + fused 1x1 score; A via LDS-DMA, B from L1/L2 ----------------
__device__ __forceinline__ void c2_stageA(const unsigned short* ht, const unsigned short* zerobuf,
                                          half8* Ab, int b, int t0, int cc, int lane, int wid)
{
    #pragma unroll
    for (int part = 0; part < 5; ++part) {
        int row = part * 64 + lane;
        int t = t0 + row - 1;
        const unsigned short* src = zerobuf;
        if (row < 258 && t >= 0 && t < T) {
            int grp = t >> 8, rin = t & 255;
            src = ht + ((size_t)((((b * 32 + grp) * 8 + cc) * 4 + wid) * 256 + rin)) * 8;
        }
        gl_lds16(src, &Ab[wid * 322 + part * 64]);
    }
}

__global__ __launch_bounds__(256, 3) void conv2_mfma(
    const unsigned short* __restrict__ h1t,
    const unsigned short* __restrict__ WbL,
    const float* __restrict__ b2, const float* __restrict__ v,
    const unsigned short* __restrict__ zerobuf,
    float* __restrict__ dlog)
{
    __shared__ half8 A8[4 * 322];        // rows 0..257 valid (t = t0+row-1)   20.6 KB
    const int tid = threadIdx.x, lane = tid & 63, wid = tid >> 6;
    const int bid = blockIdx.x;
    const int cid = (bid & 7) * 256 + (bid >> 3);
    const int xcol = cid >> 2;
    const int ycol = cid & 3;
    const int b  = xcol >> 5;
    const int t0 = (xcol & 31) << 8;
    const int h0 = ycol << 6;
    const int q = lane >> 4, l15 = lane & 15;
    const unsigned short* Wl0 = WbL + (size_t)(ycol * 8) * 12 * 512
                                + (size_t)(q * 64 + l15) * 8;

    f32x4 acc[4][4] = {};

    for (int cc = 0; cc < 8; ++cc) {
        __syncthreads();
        c2_stageA(h1t, zerobuf, A8, b, t0, cc, lane, wid);
        const unsigned short* Wl = Wl0 + (size_t)cc * 6144;
        half8 bh0[4], bh1[4];
        #pragma unroll
        for (int j = 0; j < 4; ++j) bh0[j] = *(const half8*)(Wl + j * 128);
        __syncthreads();
        #pragma unroll
        for (int kw = 0; kw < 3; ++kw) {
            half8* cur = (kw & 1) ? bh1 : bh0;
            half8* nxt = (kw & 1) ? bh0 : bh1;
            if (kw < 2) {
                #pragma unroll
                for (int j = 0; j < 4; ++j)
                    nxt[j] = *(const half8*)(Wl + (kw + 1) * 2048 + j * 128);
            }
            half8 ah[4];
            const int rbase = wid * 64 + l15 + kw;
            #pragma unroll
            for (int i = 0; i < 4; ++i) ah[i] = A8[q * 322 + rbase + i * 16];
            #pragma unroll
            for (int i = 0; i < 4; ++i)
                #pragma unroll
                for (int j = 0; j < 4; ++j)
                    acc[i][j] = __builtin_amdgcn_mfma_f32_16x16x32_f16(ah[i], cur[j], acc[i][j], 0, 0, 0);
        }
    }
    // epilogue: p = sum_h v[h]*relu(h2+b2), reduce 16 lanes per quad, atomicAdd per token
    float vv[4], bb[4];
    #pragma unroll
    for (int j = 0; j < 4; ++j) {
        int h = h0 + j * 16 + l15;
        vv[j] = v[h]; bb[j] = b2[h];
    }
    #pragma unroll
    for (int i = 0; i < 4; ++i) {
        int tb = t0 + wid * 64 + i * 16 + q * 4;
        #pragma unroll
        for (int r = 0; r < 4; ++r) {
            float s = 0.f;
            #pragma unroll
            for (int j = 0; j < 4; ++j)
                s += fmaxf(acc[i][j][r] + bb[j], 0.f) * vv[j];
            #pragma unroll
            for (int m = 1; m < 16; m <<= 1)
                s += __shfl_xor(s, m, 64);
            if (l15 == 0) atomicAdd(&dlog[b * T + tb + r], s);
        }
    }
}

// ---------------- boundary bit + uncertainty list ----------------
__global__ void boundary_kernel(const float* __restrict__ d, const int* __restrict__ padmask,
                                const float* __restrict__ b3,
                                int* __restrict__ isb, int* __restrict__ ucount,
                                int* __restrict__ ulist)
{
    int bt = blockIdx.x * 256 + threadIdx.x;
    if (bt >= BT) return;
    int pad = padmask[bt];
    float dd = d[bt] + (b3[1] - b3[0]);
    isb[bt] = (pad == 0 && dd > 0.f) ? 1 : 0;
    if (pad == 0 && fabsf(dd) < TAU) {
        int slot = atomicAdd(ucount, 1);
        if (slot < RCAP) ulist[slot] = bt;
    }
}

// ---------------- recheck phase 1: conv1 in f64, 4 blocks/candidate ----------------
__global__ __launch_bounds__(256) void recheck_h1(
    const float* __restrict__ x, const float* __restrict__ W1R,
    const float* __restrict__ b1, const float* __restrict__ zerof,
    const int* __restrict__ ulist, const int* __restrict__ ucount,
    float* __restrict__ h1f)
{
    __shared__ float xs[9 * CDIM];       // x[t-4..t+4][:], zero OOB rows
    int n = *ucount; if (n > RCAP) n = RCAP;
    const int tid = threadIdx.x, lane = tid & 63, wid = tid >> 6;
    const int g = tid >> 4, l = tid & 15;
    const int nit = 4 * n;
    for (int item = blockIdx.x; item < nit; item += gridDim.x) {
        const int li = item >> 2, hc = item & 3;
        const int bt = ulist[li];
        const int b = bt >> 13, t = bt & (T - 1);
        __syncthreads();                 // xs from previous item fully consumed
        for (int r = wid; r < 9; r += 4) {
            int tt = t + r - 4;
            const float* src = (tt >= 0 && tt < T)
                ? x + (size_t)(b * T + tt) * CDIM + lane * 4 : zerof;
            gl_lds16(src, &xs[r * CDIM]);
        }
        __syncthreads();
        #pragma unroll
        for (int s = 0; s < 4; ++s) {
            const int h = hc * 64 + s * 16 + g;
            const float* wr = &W1R[(size_t)h * 1792];
            double p0 = 0.0, p1 = 0.0, p2 = 0.0;
            #pragma unroll 7
            for (int it = 0; it < 28; ++it) {
                const int e = it * 64 + l * 4;
                float4 w4 = *(const float4*)&wr[e];
                double w0 = (double)w4.x, w1v = (double)w4.y,
                       w2v = (double)w4.z, w3v = (double)w4.w;
                const float* x0 = &xs[e];
                p0 += w0 * (double)x0[0] + w1v * (double)x0[1]
                    + w2v * (double)x0[2] + w3v * (double)x0[3];
                const float* x1 = &xs[256 + e];
                p1 += w0 * (double)x1[0] + w1v * (double)x1[1]
                    + w2v * (double)x1[2] + w3v * (double)x1[3];
                const float* x2 = &xs[512 + e];
                p2 += w0 * (double)x2[0] + w1v * (double)x2[1]
                    + w2v * (double)x2[2] + w3v * (double)x2[3];
            }
            #pragma unroll
            for (int m = 1; m < 16; m <<= 1) {
                p0 += __shfl_xor(p0, m);
                p1 += __shfl_xor(p1, m);
                p2 += __shfl_xor(p2, m);
            }
            if (l == 0) {
                double bb = (double)b1[h];
                double a0 = bb + p0, a1 = bb + p1, a2 = bb + p2;
                float* o = &h1f[(size_t)li * 768];
                o[0 * 256 + h] = (t - 1 >= 0 && a0 > 0.0) ? (float)a0 : 0.f;
                o[1 * 256 + h] = (a1 > 0.0) ? (float)a1 : 0.f;
                o[2 * 256 + h] = (t + 1 < T && a2 > 0.0) ? (float)a2 : 0.f;
            }
        }
    }
}

// ---------------- recheck phase 2: conv2 + 1x1 in f64, 4 blocks/candidate ----------------
__global__ __launch_bounds__(256) void recheck_h2(
    const float* __restrict__ h1f, const float* __restrict__ W2R,
    const float* __restrict__ b2, const float* __restrict__ w3,
    const int* __restrict__ ulist, const int* __restrict__ ucount,
    double* __restrict__ dsum)
{
    __shared__ float hs[768];
    __shared__ double red[64];
    int n = *ucount; if (n > RCAP) n = RCAP;
    const int tid = threadIdx.x, lane = tid & 63, wid = tid >> 6;
    const int g = tid >> 4, l = tid & 15;
    const int nit = 4 * n;
    for (int item = blockIdx.x; item < nit; item += gridDim.x) {
        const int li = item >> 2, hc = item & 3;
        __syncthreads();                 // hs/red from previous item consumed
        if (wid < 3)
            gl_lds16(h1f + (size_t)li * 768 + wid * 256 + lane * 4, &hs[wid * 256]);
        __syncthreads();
        #pragma unroll
        for (int s = 0; s < 4; ++s) {
            const int h = hc * 64 + s * 16 + g;
            const float* wr = &W2R[(size_t)h * 768];
            double c0 = 0.0;
            #pragma unroll
            for (int it = 0; it < 12; ++it) {
                const int e = it * 64 + l * 4;
                float4 w4 = *(const float4*)&wr[e];
                const float* hv = &hs[e];
                c0 += (double)w4.x * (double)hv[0] + (double)w4.y * (double)hv[1]
                    + (double)w4.z * (double)hv[2] + (double)w4.w * (double)hv[3];
            }
            #pragma unroll
            for (int m = 1; m < 16; m <<= 1) c0 += __shfl_xor(c0, m);
            if (l == 0) {
                double acc2 = (double)b2[h] + c0;
                double h2v = acc2 > 0.0 ? acc2 : 0.0;
                double vd = (double)w3[HDIM + h] - (double)w3[h];
                red[s * 16 + g] = vd * h2v;
            }
        }
        __syncthreads();
        if (tid < 32) red[tid] += red[tid + 32];
        __syncthreads();
        if (tid < 16) red[tid] += red[tid + 16];
        __syncthreads();
        if (tid == 0) {
            double ssum = 0.0;
            #pragma unroll
            for (int i = 0; i < 16; ++i) ssum += red[i];
            atomicAdd(&dsum[li], ssum);
        }
    }
}

// ---------------- recheck finalize ----------------
__global__ void recheck_final(const double* __restrict__ dsum, const float* __restrict__ b3,
                              const int* __restrict__ ulist, const int* __restrict__ ucount,
                              int* __restrict__ isb)
{
    int n = *ucount; if (n > RCAP) n = RCAP;
    int li = blockIdx.x * 256 + threadIdx.x;
    if (li >= n) return;
    double dd = dsum[li] + ((double)b3[1] - (double)b3[0]);
    isb[ulist[li]] = (dd > 0.0) ? 1 : 0;
}

// ---------------- per-batch inclusive cumsum -> seg_id, n_valid ----------------
__global__ __launch_bounds__(1024) void scan_kernel(
    const int* __restrict__ isb, const int* __restrict__ padmask,
    int* __restrict__ sid, int* __restrict__ nvalid)
{
    __shared__ int ssum[1024];
    const int b = blockIdx.x, tid = threadIdx.x;
    const int base = b * T;
    int vals[8]; int s = 0;
    #pragma unroll
    for (int i = 0; i < 8; ++i) { vals[i] = isb[base + tid * 8 + i]; s += vals[i]; }
    ssum[tid] = s;
    __syncthreads();
    for (int off = 1; off < 1024; off <<= 1) {
        int add = (tid >= off) ? ssum[tid - off] : 0;
        __syncthreads();
        ssum[tid] += add;
        __syncthreads();
    }
    int run = ssum[tid] - s;
    #pragma unroll
    for (int i = 0; i < 8; ++i) {
        int t = tid * 8 + i;
        run += vals[i];
        sid[base + t] = (padmask[base + t] != 0) ? T : run;
    }
    if (tid == 1023) {
        int nb = ssum[1023];
        nvalid[b] = (padmask[base] == 0) ? (nb + 1) : 0;
    }
}

// ---------------- segment range extraction ----------------
__global__ void segbounds_kernel(const int* __restrict__ sid, const int* __restrict__ padmask,
                                 int* __restrict__ sst, int* __restrict__ sen)
{
    int bt = blockIdx.x * 256 + threadIdx.x;
    if (bt >= BT) return;
    if (padmask[bt] != 0) return;
    int t = bt & (T - 1);
    int b = bt >> 13;
    int s = sid[bt];
    if (t == 0) {
        if (s < T) sst[b * T + s] = 0;
    } else if (s != sid[bt - 1]) {
        if (s < T) sst[b * T + s] = t;
    }
    bool last = (t == T - 1) || (padmask[bt + 1] != 0);
    if (s < T && (last || sid[bt + 1] != s)) sen[b * T + s] = t + 1;
}

// ---------------- segment-mean pooling + new_pad ----------------
__global__ __launch_bounds__(256) void pool_kernel(
    const float* __restrict__ x, const int* __restrict__ sst,
    const int* __restrict__ sen, const int* __restrict__ nvalid,
    float* __restrict__ out)
{
    int slot = blockIdx.x * 4 + (threadIdx.x >> 6);
    int lane = threadIdx.x & 63;
    int b = slot >> 13;
    int s = slot & (T - 1);
    int nv = nvalid[b];
    float4 res = make_float4(0.f, 0.f, 0.f, 0.f);
    if (s < nv) {
        int st = sst[slot], en = sen[slot];
        if (st >= 0 && en > st) {
            float4 a = make_float4(0.f, 0.f, 0.f, 0.f);
            const float* xp = &x[(size_t)(b * T + st) * CDIM + lane * 4];
            for (int t = st; t < en; ++t) {
                float4 xv = *(const float4*)xp;
                a.x += xv.x; a.y += xv.y; a.z += xv.z; a.w += xv.w;
                xp += CDIM;
            }
            float inv = 1.f / (float)(en - st);
            res = make_float4(a.x * inv, a.y * inv, a.z * inv, a.w * inv);
        }
    }
    *(float4*)&out[(size_t)slot * CDIM + lane * 4] = res;
    if (lane == 0) out[(size_t)BT * CDIM + slot] = (s < nv) ? 0.f : 1.f;
}

extern "C" void kernel_launch(void* const* d_in, const int* in_sizes, int n_in,
                              void* d_out, int out_size, void* d_ws, size_t ws_size,
                              hipStream_t stream)
{
    const float* x  = (const float*)d_in[0];
    const int* padmask = (const int*)d_in[1];
    const float* w1 = (const float*)d_in[2];
    const float* b1 = (const float*)d_in[3];
    const float* w2 = (const float*)d_in[4];
    const float* b2 = (const float*)d_in[5];
    const float* w3 = (const float*)d_in[6];
    const float* b3 = (const float*)d_in[7];

    char* ws = (char*)d_ws;
    float* W1R = (float*)(ws + B_W1T);
    float* W2R = (float*)(ws + B_W2T);
    float* v   = (float*)(ws + B_V);
    float* dlog = (float*)(ws + B_D);
    int* isb = (int*)(ws + B_ISB);
    int* sid = (int*)(ws + B_SID);
    int* sst = (int*)(ws + B_SST);
    int* sen = (int*)(ws + B_SEN);
    int* nv  = (int*)(ws + B_NV);
    int* uct = (int*)(ws + B_UCT);
    int* ul  = (int*)(ws + B_UL);
    unsigned short* zerobuf = (unsigned short*)(ws + B_ZERO);
    unsigned short* W1bL = (unsigned short*)(ws + B_W1B);
    unsigned short* W2bL = (unsigned short*)(ws + B_W2B);
    float* h1f = (float*)(ws + B_H1F);
    double* dsum = (double*)(ws + B_DSUM);

    float* out = (float*)d_out;
    // d_out scratch: h1t f16 tiled [BT][256] in the first half, xt f16 tiled in the second
    unsigned short* h1t = (unsigned short*)out;
    unsigned short* xt  = h1t + (size_t)BT * 256;

    hipMemsetAsync(dlog, 0, BT * sizeof(float), stream);
    hipMemsetAsync(sst, 0xFF, BT * sizeof(int), stream);
    hipMemsetAsync(sen, 0xFF, BT * sizeof(int), stream);
    hipMemsetAsync(uct, 0, sizeof(int), stream);
    hipMemsetAsync(zerobuf, 0, 256, stream);
    hipMemsetAsync(dsum, 0, RCAP * sizeof(double), stream);

    repack_kernel<<<1024, 256, 0, stream>>>(w1, w2, w3, W1R, W2R, v, W1bL, W2bL);
    xcast_kernel<<<BT * 256 / (8 * 256), 256, 0, stream>>>(x, xt);
    conv1_mfma<<<2048, 256, 0, stream>>>(xt, W1bL, b1, zerobuf, h1t);
    conv2_mfma<<<2048, 256, 0, stream>>>(h1t, W2bL, b2, v, zerobuf, dlog);
    boundary_kernel<<<BT / 256, 256, 0, stream>>>(dlog, padmask, b3, isb, uct, ul);
    recheck_h1<<<4096, 256, 0, stream>>>(x, W1R, b1, (const float*)zerobuf, ul, uct, h1f);
    recheck_h2<<<4096, 256, 0, stream>>>(h1f, W2R, b2, w3, ul, uct, dsum);
    recheck_final<<<RCAP / 256, 256, 0, stream>>>(dsum, b3, ul, uct, isb);
    scan_kernel<<<BSZ, 1024, 0, stream>>>(isb, padmask, sid, nv);
    segbounds_kernel<<<BT / 256, 256, 0, stream>>>(sid, padmask, sst, sen);
    pool_kernel<<<BT / 4, 256, 0, stream>>>(x, sst, sen, nv, out);
}

// Round 10
// 587.919 us; speedup vs baseline: 1.0426x; 1.0426x over previous
//
#include <hip/hip_runtime.h>
#include <cstdint>
#include <cstddef>

#define BSZ 16
#define T   8192
#define CDIM 256
#define HDIM 256
#define KW  7

constexpr int BT = BSZ * T;                  // 131072
constexpr float TAU = 2e-3f;                 // f64 recheck band for |d| (fp16 path: sigma_d ~1.5e-4, band ~13 sigma)
constexpr int RCAP = 8192;                   // recheck candidate cap (measured n ~ O(1000))

typedef __attribute__((ext_vector_type(8))) short short8;
typedef _Float16 half8 __attribute__((ext_vector_type(8)));
typedef __attribute__((ext_vector_type(4))) float f32x4;

// ---------------- workspace layout (byte offsets, all 16B-aligned) ----------------
constexpr size_t B_W1T  = 0;                         // f32 [256][7*256]  1835008 B ([h][k*256+c], recheck)
constexpr size_t B_W2T  = B_W1T + 1835008;           // f32 [256][3*256]   786432 B ([h][k*256+c])
constexpr size_t B_V    = B_W2T + 786432;            // f32 [256]
constexpr size_t B_D    = B_V + 1024;                // f32 [BT]
constexpr size_t B_ISB  = B_D + 524288;              // i32 [BT]
constexpr size_t B_SID  = B_ISB + 524288;            // i32 [BT]
constexpr size_t B_SST  = B_SID + 524288;            // i32 [BT]
constexpr size_t B_SEN  = B_SST + 524288;            // i32 [BT]
constexpr size_t B_NV   = B_SEN + 524288;            // i32 [16]
constexpr size_t B_UCT  = B_NV + 64;                 // i32 [1]
constexpr size_t B_UL   = B_UCT + 16;                // i32 [RCAP]    32768 B
constexpr size_t B_ZERO = B_UL + 32768;              // 256 B of zeros (DMA clamp target)
constexpr size_t B_W1B  = B_ZERO + 256;              // f16 DMA-linear [4][8][28][64][8]  917504 B
constexpr size_t B_W2B  = B_W1B + 917504;            // f16 DMA-linear [4][8][12][64][8]  393216 B
constexpr size_t B_H1F  = B_W2B + 393216;            // f32 [RCAP][3][256] 25165824 B (recheck h1 scratch)
constexpr size_t B_DSUM = B_H1F + 25165824;          // f64 [RCAP]          65536 B  -> ~31.8 MB total

// async global->LDS, 16B per lane; LDS dest = wave-uniform base + lane*16 (global addr per-lane)
__device__ __forceinline__ void gl_lds16(const void* g, void* l) {
    __builtin_amdgcn_global_load_lds(
        (const __attribute__((address_space(1))) unsigned int*)g,
        (__attribute__((address_space(3))) unsigned int*)l,
        16, 0, 0);
}

// f32 -> f16 RNE (hardware default round mode for v_cvt_f16_f32)
__device__ __forceinline__ unsigned short f16_rne(float f) {
    _Float16 h = (_Float16)f;
    return __builtin_bit_cast(unsigned short, h);
}

// Tiled f16 activation layout (xt and h1t): halfword index of (b, t, c) =
//   ((((b*32 + (t>>8))*8 + (c>>5))*4 + ((c>>3)&3))*256 + (t&255))*8 + (c&7)
// -> A-stage lanes (consecutive t, fixed 8-c chunk) read contiguous 16B chunks.

// ---------------- weight repack ----------------
// W1R/W2R: f32 [h][kw*256+c] for f64 recheck. W1bL/W2bL: f16 in DMA-emission order
// [h0g(4)][cc(8)][slot=kw*4+bq][lane=h(64)][8e]  (h = h0g*64+lane, c = cc*32+bq*8+e)
__global__ void repack_kernel(const float* __restrict__ w1, const float* __restrict__ w2,
                              const float* __restrict__ w3,
                              float* __restrict__ W1R, float* __restrict__ W2R,
                              float* __restrict__ v,
                              unsigned short* __restrict__ W1bL, unsigned short* __restrict__ W2bL)
{
    int idx = blockIdx.x * blockDim.x + threadIdx.x;
    int stride = gridDim.x * blockDim.x;
    for (int i = idx; i < HDIM * 1792; i += stride) {
        int h = i / 1792, kc = i % 1792, kw = kc >> 8, c = kc & 255;
        W1R[i] = w1[(size_t)h * 1792 + c * 7 + kw];
    }
    for (int i = idx; i < HDIM * 768; i += stride) {
        int h = i / 768, kc = i % 768, kw = kc >> 8, c = kc & 255;
        W2R[i] = w2[(size_t)h * 768 + c * 3 + kw];
    }
    for (int o = idx; o < 4 * 8 * 28 * 512; o += stride) {
        int e = o & 7, lane = (o >> 3) & 63;
        int su = o >> 9;
        int slot = su % 28, rest = su / 28;
        int cc = rest & 7, h0g = rest >> 3;
        int kw = slot >> 2, bq = slot & 3;
        int h = h0g * 64 + lane;
        int c = cc * 32 + bq * 8 + e;
        W1bL[o] = f16_rne(w1[(size_t)h * 1792 + c * 7 + kw]);
    }
    for (int o = idx; o < 4 * 8 * 12 * 512; o += stride) {
        int e = o & 7, lane = (o >> 3) & 63;
        int su = o >> 9;
        int slot = su % 12, rest = su / 12;
        int cc = rest & 7, h0g = rest >> 3;
        int kw = slot >> 2, bq = slot & 3;
        int h = h0g * 64 + lane;
        int c = cc * 32 + bq * 8 + e;
        W2bL[o] = f16_rne(w2[(size_t)h * 768 + c * 3 + kw]);
    }
    if (idx < HDIM) v[idx] = w3[HDIM + idx] - w3[idx];
}

// ---------------- x -> f16 tiled layout (output-indexed, coalesced 16B writes) ----------------
__global__ __launch_bounds__(256) void xcast_kernel(const float* __restrict__ x,
                                                    unsigned short* __restrict__ xt)
{
    int j = blockIdx.x * 256 + threadIdx.x;      // 8-half chunk index, [b][grp][cc][wid][rin]
    int rin = j & 255, wid = (j >> 8) & 3, cc = (j >> 10) & 7, grp = (j >> 13) & 31, b = j >> 18;
    int t = grp * 256 + rin;
    int c0 = cc * 32 + wid * 8;
    const float* src = x + ((size_t)(b * T + t)) * 256 + c0;
    float4 a = *(const float4*)src;
    float4 bb = *(const float4*)(src + 4);
    short8 o;
    o[0] = (short)f16_rne(a.x); o[1] = (short)f16_rne(a.y);
    o[2] = (short)f16_rne(a.z); o[3] = (short)f16_rne(a.w);
    o[4] = (short)f16_rne(bb.x); o[5] = (short)f16_rne(bb.y);
    o[6] = (short)f16_rne(bb.z); o[7] = (short)f16_rne(bb.w);
    *(short8*)(xt + (size_t)j * 8) = o;
}

// ---------------- conv1: f16 MFMA, 256t x 64h, B-in-LDS, 3 blocks/CU, XCD swizzle ----------------
// Round-8 structure (B via LDS DMA: decouples weight delivery from the MFMA pipe;
// measured 110us/50% MfmaUtil) + round-9 XCD swizzle (measured FETCH 135->42MB:
// the 4 y-siblings of an xt panel land on one XCD's L2). B-direct (r9) regressed:
// 1-deep reg prefetch can't cover L1/L2 latency and 3 ycols thrash L1.
__device__ __forceinline__ void c1_stageA(const unsigned short* xt, const unsigned short* zerobuf,
                                          half8* Ab, int b, int t0, int cc, int lane, int wid)
{
    #pragma unroll
    for (int part = 0; part < 5; ++part) {
        int row = part * 64 + lane;
        int t = t0 + row - 3;
        const unsigned short* src = zerobuf;
        if (row < 262 && t >= 0 && t < T) {
            int grp = t >> 8, rin = t & 255;
            src = xt + ((size_t)((((b * 32 + grp) * 8 + cc) * 4 + wid) * 256 + rin)) * 8;
        }
        gl_lds16(src, &Ab[wid * 322 + part * 64]);
    }
}
__device__ __forceinline__ void c1_stageB(const unsigned short* WbL, half8* Bb,
                                          int hcc, int lane, int wid)
{
    #pragma unroll
    for (int s = 0; s < 7; ++s) {
        int slot = wid * 7 + s;
        const unsigned short* src = WbL + ((size_t)(hcc * 28 + slot)) * 512 + lane * 8;
        gl_lds16(src, &Bb[slot * 66]);
    }
}

__global__ __launch_bounds__(256, 3) void conv1_mfma(
    const unsigned short* __restrict__ xt,
    const unsigned short* __restrict__ WbL,
    const float* __restrict__ b1,
    const unsigned short* __restrict__ zerobuf,
    unsigned short* __restrict__ h1t)
{
    __shared__ half8 A8[4 * 322];        // [q][row], rows 0..261 valid (t = t0+row-3)  20.6 KB
    __shared__ half8 B8[28 * 66];        // [kw*4+bq][h]                                29.6 KB
    const int tid = threadIdx.x, lane = tid & 63, wid = tid >> 6;
    // XCD-aware bijective swizzle (2048 % 8 == 0): XCD k processes cids [k*256,(k+1)*256);
    // ycol fastest -> 4 y-siblings of an xt panel share one XCD's L2.
    const int bid = blockIdx.x;
    const int cid = (bid & 7) * 256 + (bid >> 3);
    const int xcol = cid >> 2;           // 0..511 = b*32+grp
    const int ycol = cid & 3;            // h-group
    const int b  = xcol >> 5;
    const int grp = xcol & 31;
    const int t0 = grp << 8;
    const int h0 = ycol << 6;
    const int q = lane >> 4, l15 = lane & 15;

    f32x4 acc[4][4] = {};

    for (int cc = 0; cc < 8; ++cc) {
        __syncthreads();                 // previous compute fully consumed LDS
        c1_stageA(xt, zerobuf, A8, b, t0, cc, lane, wid);
        c1_stageB(WbL, B8, ycol * 8 + cc, lane, wid);
        __syncthreads();                 // drain DMAs
        #pragma unroll
        for (int kw = 0; kw < 7; ++kw) {
            half8 ah[4], bh[4];
            const int rbase = wid * 64 + l15 + kw;
            #pragma unroll
            for (int i = 0; i < 4; ++i) ah[i] = A8[q * 322 + rbase + i * 16];
            #pragma unroll
            for (int j = 0; j < 4; ++j) bh[j] = B8[(kw * 4 + q) * 66 + j * 16 + l15];
            #pragma unroll
            for (int i = 0; i < 4; ++i)
                #pragma unroll
                for (int j = 0; j < 4; ++j)
                    acc[i][j] = __builtin_amdgcn_mfma_f32_16x16x32_f16(ah[i], bh[j], acc[i][j], 0, 0, 0);
        }
    }
    // epilogue: bias+relu, store h1 f16 in the tiled layout
    #pragma unroll
    for (int j = 0; j < 4; ++j) {
        int h = h0 + j * 16 + l15;
        float bb = b1[h];
        int hcc = h >> 5, hwid = (h >> 3) & 3, he = h & 7;
        size_t hbase = ((size_t)(((b * 32 + grp) * 8 + hcc) * 4 + hwid)) * 2048 + he;
        #pragma unroll
        for (int i = 0; i < 4; ++i) {
            int rb = wid * 64 + i * 16 + q * 4;    // rin
            #pragma unroll
            for (int r = 0; r < 4; ++r)
                h1t[hbase + (size_t)(rb + r) * 8] = f16_rne(fmaxf(acc[i][j][r] + bb, 0.f));
        }
    }
}

// ---------------- conv2: f16 MFMA + fused 1x1 score, B-in-LDS, 3 blocks/CU, XCD swizzle ----------------
__device__ __forceinline__ void c2_stageA(const unsigned short* ht, const unsigned short* zerobuf,
                                          half8* Ab, int b, int t0, int cc, int lane, int wid)
{
    #pragma unroll
    for (int part = 0; part < 5; ++part) {
        int row = part * 64 + lane;
        int t = t0 + row - 1;
        const unsigned short* src = zerobuf;
        if (row < 258 && t >= 0 && t < T) {
            int grp = t >> 8, rin = t & 255;
            src = ht + ((size_t)((((b * 32 + grp) * 8 + cc) * 4 + wid) * 256 + rin)) * 8;
        }
        gl_lds16(src, &Ab[wid * 322 + part * 64]);
    }
}
__device__ __forceinline__ void c2_stageB(const unsigned short* WbL, half8* Bb,
                                          int hcc, int lane, int wid)
{
    #pragma unroll
    for (int s = 0; s < 3; ++s) {
        int slot = wid * 3 + s;
        const unsigned short* src = WbL + ((size_t)(hcc * 12 + slot)) * 512 + lane * 8;
        gl_lds16(src, &Bb[slot * 66]);
    }
}

__global__ __launch_bounds__(256, 3) void conv2_mfma(
    const unsigned short* __restrict__ h1t,
    const unsigned short* __restrict__ WbL,
    const float* __restrict__ b2, const float* __restrict__ v,
    const unsigned short* __restrict__ zerobuf,
    float* __restrict__ dlog)
{
    __shared__ half8 A8[4 * 322];        // rows 0..257 valid (t = t0+row-1)   20.6 KB
    __shared__ half8 B8[12 * 66];        // 3 kw x 4 bq x 66                   12.7 KB
    const int tid = threadIdx.x, lane = tid & 63, wid = tid >> 6;
    const int bid = blockIdx.x;
    const int cid = (bid & 7) * 256 + (bid >> 3);
    const int xcol = cid >> 2;
    const int ycol = cid & 3;
    const int b  = xcol >> 5;
    const int t0 = (xcol & 31) << 8;
    const int h0 = ycol << 6;
    const int q = lane >> 4, l15 = lane & 15;

    f32x4 acc[4][4] = {};

    for (int cc = 0; cc < 8; ++cc) {
        __syncthreads();
        c2_stageA(h1t, zerobuf, A8, b, t0, cc, lane, wid);
        c2_stageB(WbL, B8, ycol * 8 + cc, lane, wid);
        __syncthreads();
        #pragma unroll
        for (int kw = 0; kw < 3; ++kw) {
            half8 ah[4], bh[4];
            const int rbase = wid * 64 + l15 + kw;
            #pragma unroll
            for (int i = 0; i < 4; ++i) ah[i] = A8[q * 322 + rbase + i * 16];
            #pragma unroll
            for (int j = 0; j < 4; ++j) bh[j] = B8[(kw * 4 + q) * 66 + j * 16 + l15];
            #pragma unroll
            for (int i = 0; i < 4; ++i)
                #pragma unroll
                for (int j = 0; j < 4; ++j)
                    acc[i][j] = __builtin_amdgcn_mfma_f32_16x16x32_f16(ah[i], bh[j], acc[i][j], 0, 0, 0);
        }
    }
    // epilogue: p = sum_h v[h]*relu(h2+b2), reduce 16 lanes per quad, atomicAdd per token
    float vv[4], bb[4];
    #pragma unroll
    for (int j = 0; j < 4; ++j) {
        int h = h0 + j * 16 + l15;
        vv[j] = v[h]; bb[j] = b2[h];
    }
    #pragma unroll
    for (int i = 0; i < 4; ++i) {
        int tb = t0 + wid * 64 + i * 16 + q * 4;
        #pragma unroll
        for (int r = 0; r < 4; ++r) {
            float s = 0.f;
            #pragma unroll
            for (int j = 0; j < 4; ++j)
                s += fmaxf(acc[i][j][r] + bb[j], 0.f) * vv[j];
            #pragma unroll
            for (int m = 1; m < 16; m <<= 1)
                s += __shfl_xor(s, m, 64);
            if (l15 == 0) atomicAdd(&dlog[b * T + tb + r], s);
        }
    }
}

// ---------------- boundary bit + uncertainty list ----------------
__global__ void boundary_kernel(const float* __restrict__ d, const int* __restrict__ padmask,
                                const float* __restrict__ b3,
                                int* __restrict__ isb, int* __restrict__ ucount,
                                int* __restrict__ ulist)
{
    int bt = blockIdx.x * 256 + threadIdx.x;
    if (bt >= BT) return;
    int pad = padmask[bt];
    float dd = d[bt] + (b3[1] - b3[0]);
    isb[bt] = (pad == 0 && dd > 0.f) ? 1 : 0;
    if (pad == 0 && fabsf(dd) < TAU) {
        int slot = atomicAdd(ucount, 1);
        if (slot < RCAP) ulist[slot] = bt;
    }
}

// ---------------- recheck phase 1: conv1 in f64, 4 blocks/candidate ----------------
__global__ __launch_bounds__(256) void recheck_h1(
    const float* __restrict__ x, const float* __restrict__ W1R,
    const float* __restrict__ b1, const float* __restrict__ zerof,
    const int* __restrict__ ulist, const int* __restrict__ ucount,
    float* __restrict__ h1f)
{
    __shared__ float xs[9 * CDIM];       // x[t-4..t+4][:], zero OOB rows
    int n = *ucount; if (n > RCAP) n = RCAP;
    const int tid = threadIdx.x, lane = tid & 63, wid = tid >> 6;
    const int g = tid >> 4, l = tid & 15;
    const int nit = 4 * n;
    for (int item = blockIdx.x; item < nit; item += gridDim.x) {
        const int li = item >> 2, hc = item & 3;
        const int bt = ulist[li];
        const int b = bt >> 13, t = bt & (T - 1);
        __syncthreads();                 // xs from previous item fully consumed
        for (int r = wid; r < 9; r += 4) {
            int tt = t + r - 4;
            const float* src = (tt >= 0 && tt < T)
                ? x + (size_t)(b * T + tt) * CDIM + lane * 4 : zerof;
            gl_lds16(src, &xs[r * CDIM]);
        }
        __syncthreads();
        #pragma unroll
        for (int s = 0; s < 4; ++s) {
            const int h = hc * 64 + s * 16 + g;
            const float* wr = &W1R[(size_t)h * 1792];
            double p0 = 0.0, p1 = 0.0, p2 = 0.0;
            #pragma unroll 7
            for (int it = 0; it < 28; ++it) {
                const int e = it * 64 + l * 4;
                float4 w4 = *(const float4*)&wr[e];
                double w0 = (double)w4.x, w1v = (double)w4.y,
                       w2v = (double)w4.z, w3v = (double)w4.w;
                const float* x0 = &xs[e];
                p0 += w0 * (double)x0[0] + w1v * (double)x0[1]
                    + w2v * (double)x0[2] + w3v * (double)x0[3];
                const float* x1 = &xs[256 + e];
                p1 += w0 * (double)x1[0] + w1v * (double)x1[1]
                    + w2v * (double)x1[2] + w3v * (double)x1[3];
                const float* x2 = &xs[512 + e];
                p2 += w0 * (double)x2[0] + w1v * (double)x2[1]
                    + w2v * (double)x2[2] + w3v * (double)x2[3];
            }
            #pragma unroll
            for (int m = 1; m < 16; m <<= 1) {
                p0 += __shfl_xor(p0, m);
                p1 += __shfl_xor(p1, m);
                p2 += __shfl_xor(p2, m);
            }
            if (l == 0) {
                double bb = (double)b1[h];
                double a0 = bb + p0, a1 = bb + p1, a2 = bb + p2;
                float* o = &h1f[(size_t)li * 768];
                o[0 * 256 + h] = (t - 1 >= 0 && a0 > 0.0) ? (float)a0 : 0.f;
                o[1 * 256 + h] = (a1 > 0.0) ? (float)a1 : 0.f;
                o[2 * 256 + h] = (t + 1 < T && a2 > 0.0) ? (float)a2 : 0.f;
            }
        }
    }
}

// ---------------- recheck phase 2: conv2 + 1x1 in f64, 4 blocks/candidate ----------------
__global__ __launch_bounds__(256) void recheck_h2(
    const float* __restrict__ h1f, const float* __restrict__ W2R,
    const float* __restrict__ b2, const float* __restrict__ w3,
    const int* __restrict__ ulist, const int* __restrict__ ucount,
    double* __restrict__ dsum)
{
    __shared__ float hs[768];
    __shared__ double red[64];
    int n = *ucount; if (n > RCAP) n = RCAP;
    const int tid = threadIdx.x, lane = tid & 63, wid = tid >> 6;
    const int g = tid >> 4, l = tid & 15;
    const int nit = 4 * n;
    for (int item = blockIdx.x; item < nit; item += gridDim.x) {
        const int li = item >> 2, hc = item & 3;
        __syncthreads();                 // hs/red from previous item consumed
        if (wid < 3)
            gl_lds16(h1f + (size_t)li * 768 + wid * 256 + lane * 4, &hs[wid * 256]);
        __syncthreads();
        #pragma unroll
        for (int s = 0; s < 4; ++s) {
            const int h = hc * 64 + s * 16 + g;
            const float* wr = &W2R[(size_t)h * 768];
            double c0 = 0.0;
            #pragma unroll
            for (int it = 0; it < 12; ++it) {
                const int e = it * 64 + l * 4;
                float4 w4 = *(const float4*)&wr[e];
                const float* hv = &hs[e];
                c0 += (double)w4.x * (double)hv[0] + (double)w4.y * (double)hv[1]
                    + (double)w4.z * (double)hv[2] + (double)w4.w * (double)hv[3];
            }
            #pragma unroll
            for (int m = 1; m < 16; m <<= 1) c0 += __shfl_xor(c0, m);
            if (l == 0) {
                double acc2 = (double)b2[h] + c0;
                double h2v = acc2 > 0.0 ? acc2 : 0.0;
                double vd = (double)w3[HDIM + h] - (double)w3[h];
                red[s * 16 + g] = vd * h2v;
            }
        }
        __syncthreads();
        if (tid < 32) red[tid] += red[tid + 32];
        __syncthreads();
        if (tid < 16) red[tid] += red[tid + 16];
        __syncthreads();
        if (tid == 0) {
            double ssum = 0.0;
            #pragma unroll
            for (int i = 0; i < 16; ++i) ssum += red[i];
            atomicAdd(&dsum[li], ssum);
        }
    }
}

// ---------------- recheck finalize ----------------
__global__ void recheck_final(const double* __restrict__ dsum, const float* __restrict__ b3,
                              const int* __restrict__ ulist, const int* __restrict__ ucount,
                              int* __restrict__ isb)
{
    int n = *ucount; if (n > RCAP) n = RCAP;
    int li = blockIdx.x * 256 + threadIdx.x;
    if (li >= n) return;
    double dd = dsum[li] + ((double)b3[1] - (double)b3[0]);
    isb[ulist[li]] = (dd > 0.0) ? 1 : 0;
}

// ---------------- per-batch inclusive cumsum -> seg_id, n_valid ----------------
__global__ __launch_bounds__(1024) void scan_kernel(
    const int* __restrict__ isb, const int* __restrict__ padmask,
    int* __restrict__ sid, int* __restrict__ nvalid)
{
    __shared__ int ssum[1024];
    const int b = blockIdx.x, tid = threadIdx.x;
    const int base = b * T;
    int vals[8]; int s = 0;
    #pragma unroll
    for (int i = 0; i < 8; ++i) { vals[i] = isb[base + tid * 8 + i]; s += vals[i]; }
    ssum[tid] = s;
    __syncthreads();
    for (int off = 1; off < 1024; off <<= 1) {
        int add = (tid >= off) ? ssum[tid - off] : 0;
        __syncthreads();
        ssum[tid] += add;
        __syncthreads();
    }
    int run = ssum[tid] - s;
    #pragma unroll
    for (int i = 0; i < 8; ++i) {
        int t = tid * 8 + i;
        run += vals[i];
        sid[base + t] = (padmask[base + t] != 0) ? T : run;
    }
    if (tid == 1023) {
        int nb = ssum[1023];
        nvalid[b] = (padmask[base] == 0) ? (nb + 1) : 0;
    }
}

// ---------------- segment range extraction ----------------
__global__ void segbounds_kernel(const int* __restrict__ sid, const int* __restrict__ padmask,
                                 int* __restrict__ sst, int* __restrict__ sen)
{
    int bt = blockIdx.x * 256 + threadIdx.x;
    if (bt >= BT) return;
    if (padmask[bt] != 0) return;
    int t = bt & (T - 1);
    int b = bt >> 13;
    int s = sid[bt];
    if (t == 0) {
        if (s < T) sst[b * T + s] = 0;
    } else if (s != sid[bt - 1]) {
        if (s < T) sst[b * T + s] = t;
    }
    bool last = (t == T - 1) || (padmask[bt + 1] != 0);
    if (s < T && (last || sid[bt + 1] != s)) sen[b * T + s] = t + 1;
}

// ---------------- segment-mean pooling + new_pad ----------------
__global__ __launch_bounds__(256) void pool_kernel(
    const float* __restrict__ x, const int* __restrict__ sst,
    const int* __restrict__ sen, const int* __restrict__ nvalid,
    float* __restrict__ out)
{
    int slot = blockIdx.x * 4 + (threadIdx.x >> 6);
    int lane = threadIdx.x & 63;
    int b = slot >> 13;
    int s = slot & (T - 1);
    int nv = nvalid[b];
    float4 res = make_float4(0.f, 0.f, 0.f, 0.f);
    if (s < nv) {
        int st = sst[slot], en = sen[slot];
        if (st >= 0 && en > st) {
            float4 a = make_float4(0.f, 0.f, 0.f, 0.f);
            const float* xp = &x[(size_t)(b * T + st) * CDIM + lane * 4];
            for (int t = st; t < en; ++t) {
                float4 xv = *(const float4*)xp;
                a.x += xv.x; a.y += xv.y; a.z += xv.z; a.w += xv.w;
                xp += CDIM;
            }
            float inv = 1.f / (float)(en - st);
            res = make_float4(a.x * inv, a.y * inv, a.z * inv, a.w * inv);
        }
    }
    *(float4*)&out[(size_t)slot * CDIM + lane * 4] = res;
    if (lane == 0) out[(size_t)BT * CDIM + slot] = (s < nv) ? 0.f : 1.f;
}

extern "C" void kernel_launch(void* const* d_in, const int* in_sizes, int n_in,
                              void* d_out, int out_size, void* d_ws, size_t ws_size,
                              hipStream_t stream)
{
    const float* x  = (const float*)d_in[0];
    const int* padmask = (const int*)d_in[1];
    const float* w1 = (const float*)d_in[2];
    const float* b1 = (const float*)d_in[3];
    const float* w2 = (const float*)d_in[4];
    const float* b2 = (const float*)d_in[5];
    const float* w3 = (const float*)d_in[6];
    const float* b3 = (const float*)d_in[7];

    char* ws = (char*)d_ws;
    float* W1R = (float*)(ws + B_W1T);
    float* W2R = (float*)(ws + B_W2T);
    float* v   = (float*)(ws + B_V);
    float* dlog = (float*)(ws + B_D);
    int* isb = (int*)(ws + B_ISB);
    int* sid = (int*)(ws + B_SID);
    int* sst = (int*)(ws + B_SST);
    int* sen = (int*)(ws + B_SEN);
    int* nv  = (int*)(ws + B_NV);
    int* uct = (int*)(ws + B_UCT);
    int* ul  = (int*)(ws + B_UL);
    unsigned short* zerobuf = (unsigned short*)(ws + B_ZERO);
    unsigned short* W1bL = (unsigned short*)(ws + B_W1B);
    unsigned short* W2bL = (unsigned short*)(ws + B_W2B);
    float* h1f = (float*)(ws + B_H1F);
    double* dsum = (double*)(ws + B_DSUM);

    float* out = (float*)d_out;
    // d_out scratch: h1t f16 tiled [BT][256] in the first half, xt f16 tiled in the second
    unsigned short* h1t = (unsigned short*)out;
    unsigned short* xt  = h1t + (size_t)BT * 256;

    hipMemsetAsync(dlog, 0, BT * sizeof(float), stream);
    hipMemsetAsync(sst, 0xFF, BT * sizeof(int), stream);
    hipMemsetAsync(sen, 0xFF, BT * sizeof(int), stream);
    hipMemsetAsync(uct, 0, sizeof(int), stream);
    hipMemsetAsync(zerobuf, 0, 256, stream);
    hipMemsetAsync(dsum, 0, RCAP * sizeof(double), stream);

    repack_kernel<<<1024, 256, 0, stream>>>(w1, w2, w3, W1R, W2R, v, W1bL, W2bL);
    xcast_kernel<<<BT * 256 / (8 * 256), 256, 0, stream>>>(x, xt);
    conv1_mfma<<<2048, 256, 0, stream>>>(xt, W1bL, b1, zerobuf, h1t);
    conv2_mfma<<<2048, 256, 0, stream>>>(h1t, W2bL, b2, v, zerobuf, dlog);
    boundary_kernel<<<BT / 256, 256, 0, stream>>>(dlog, padmask, b3, isb, uct, ul);
    recheck_h1<<<4096, 256, 0, stream>>>(x, W1R, b1, (const float*)zerobuf, ul, uct, h1f);
    recheck_h2<<<4096, 256, 0, stream>>>(h1f, W2R, b2, w3, ul, uct, dsum);
    recheck_final<<<RCAP / 256, 256, 0, stream>>>(dsum, b3, ul, uct, isb);
    scan_kernel<<<BSZ, 1024, 0, stream>>>(isb, padmask, sid, nv);
    segbounds_kernel<<<BT / 256, 256, 0, stream>>>(sid, padmask, sst, sen);
    pool_kernel<<<BT / 4, 256, 0, stream>>>(x, sst, sen, nv, out);
}

// Round 11
// 576.643 us; speedup vs baseline: 1.0630x; 1.0196x over previous
//
#include <hip/hip_runtime.h>
#include <cstdint>
#include <cstddef>

#define BSZ 16
#define T   8192
#define CDIM 256
#define HDIM 256
#define KW  7

constexpr int BT = BSZ * T;                  // 131072
constexpr float TAU = 2e-3f;                 // f64 recheck band for |d| (fp16 path: sigma_d ~1.5e-4, band ~13 sigma)
constexpr int RCAP = 8192;                   // recheck candidate cap (measured n ~ O(1000))

typedef __attribute__((ext_vector_type(8))) short short8;
typedef _Float16 half8 __attribute__((ext_vector_type(8)));
typedef __attribute__((ext_vector_type(4))) float f32x4;

// ---------------- workspace layout (byte offsets, all 16B-aligned) ----------------
constexpr size_t B_W1T  = 0;                         // f32 [256][7*256]  1835008 B ([h][k*256+c], recheck)
constexpr size_t B_W2T  = B_W1T + 1835008;           // f32 [256][3*256]   786432 B ([h][k*256+c])
constexpr size_t B_V    = B_W2T + 786432;            // f32 [256]
constexpr size_t B_D    = B_V + 1024;                // f32 [BT]
constexpr size_t B_ISB  = B_D + 524288;              // i32 [BT]
constexpr size_t B_SID  = B_ISB + 524288;            // i32 [BT]
constexpr size_t B_SST  = B_SID + 524288;            // i32 [BT]
constexpr size_t B_SEN  = B_SST + 524288;            // i32 [BT]
constexpr size_t B_NV   = B_SEN + 524288;            // i32 [16]
constexpr size_t B_UCT  = B_NV + 64;                 // i32 [1]
constexpr size_t B_UL   = B_UCT + 16;                // i32 [RCAP]    32768 B
constexpr size_t B_ZERO = B_UL + 32768;              // 256 B of zeros (DMA clamp target)
constexpr size_t B_W1B  = B_ZERO + 256;              // f16 DMA-linear [4][8][28][64][8]     917504 B (conv1, 64h tiles)
constexpr size_t B_W2B  = B_W1B + 917504;            // f16 DMA-linear [2][8][12][2][64][8]  393216 B (conv2, 128h tiles)
constexpr size_t B_H1F  = B_W2B + 393216;            // f32 [RCAP][3][256] 25165824 B (recheck h1 scratch)
constexpr size_t B_DSUM = B_H1F + 25165824;          // f64 [RCAP]          65536 B  -> ~31.8 MB total

// async global->LDS, 16B per lane; LDS dest = wave-uniform base + lane*16 (global addr per-lane)
__device__ __forceinline__ void gl_lds16(const void* g, void* l) {
    __builtin_amdgcn_global_load_lds(
        (const __attribute__((address_space(1))) unsigned int*)g,
        (__attribute__((address_space(3))) unsigned int*)l,
        16, 0, 0);
}

// f32 -> f16 RNE (hardware default round mode for v_cvt_f16_f32)
__device__ __forceinline__ unsigned short f16_rne(float f) {
    _Float16 h = (_Float16)f;
    return __builtin_bit_cast(unsigned short, h);
}

// Tiled f16 activation layout (xt and h1t): halfword index of (b, t, c) =
//   ((((b*32 + (t>>8))*8 + (c>>5))*4 + ((c>>3)&3))*256 + (t&255))*8 + (c&7)
// -> A-stage lanes (consecutive t, fixed 8-c chunk) read contiguous 16B chunks.

// ---------------- weight repack ----------------
// W1R/W2R: f32 [h][kw*256+c] for f64 recheck.
// W1bL: f16 [h0g(4)][cc(8)][slot=kw*4+bq][lane=h(64)][8e]        (conv1: 64h tile)
// W2bL: f16 [h0g(2)][cc(8)][slot=kw*4+bq][half(2)][lane(64)][8e] (conv2: 128h tile)
__global__ void repack_kernel(const float* __restrict__ w1, const float* __restrict__ w2,
                              const float* __restrict__ w3,
                              float* __restrict__ W1R, float* __restrict__ W2R,
                              float* __restrict__ v,
                              unsigned short* __restrict__ W1bL, unsigned short* __restrict__ W2bL)
{
    int idx = blockIdx.x * blockDim.x + threadIdx.x;
    int stride = gridDim.x * blockDim.x;
    for (int i = idx; i < HDIM * 1792; i += stride) {
        int h = i / 1792, kc = i % 1792, kw = kc >> 8, c = kc & 255;
        W1R[i] = w1[(size_t)h * 1792 + c * 7 + kw];
    }
    for (int i = idx; i < HDIM * 768; i += stride) {
        int h = i / 768, kc = i % 768, kw = kc >> 8, c = kc & 255;
        W2R[i] = w2[(size_t)h * 768 + c * 3 + kw];
    }
    for (int o = idx; o < 4 * 8 * 28 * 512; o += stride) {
        int e = o & 7, lane = (o >> 3) & 63;
        int su = o >> 9;
        int slot = su % 28, rest = su / 28;
        int cc = rest & 7, h0g = rest >> 3;
        int kw = slot >> 2, bq = slot & 3;
        int h = h0g * 64 + lane;
        int c = cc * 32 + bq * 8 + e;
        W1bL[o] = f16_rne(w1[(size_t)h * 1792 + c * 7 + kw]);
    }
    for (int o = idx; o < 2 * 8 * 12 * 1024; o += stride) {
        int e = o & 7, lane = (o >> 3) & 63, half = (o >> 9) & 1;
        int su = o >> 10;
        int slot = su % 12, rest = su / 12;
        int cc = rest & 7, h0g = rest >> 3;
        int kw = slot >> 2, bq = slot & 3;
        int h = h0g * 128 + half * 64 + lane;
        int c = cc * 32 + bq * 8 + e;
        W2bL[o] = f16_rne(w2[(size_t)h * 768 + c * 3 + kw]);
    }
    if (idx < HDIM) v[idx] = w3[HDIM + idx] - w3[idx];
}

// ---------------- x -> f16 tiled layout (output-indexed, coalesced 16B writes) ----------------
__global__ __launch_bounds__(256) void xcast_kernel(const float* __restrict__ x,
                                                    unsigned short* __restrict__ xt)
{
    int j = blockIdx.x * 256 + threadIdx.x;      // 8-half chunk index, [b][grp][cc][wid][rin]
    int rin = j & 255, wid = (j >> 8) & 3, cc = (j >> 10) & 7, grp = (j >> 13) & 31, b = j >> 18;
    int t = grp * 256 + rin;
    int c0 = cc * 32 + wid * 8;
    const float* src = x + ((size_t)(b * T + t)) * 256 + c0;
    float4 a = *(const float4*)src;
    float4 bb = *(const float4*)(src + 4);
    short8 o;
    o[0] = (short)f16_rne(a.x); o[1] = (short)f16_rne(a.y);
    o[2] = (short)f16_rne(a.z); o[3] = (short)f16_rne(a.w);
    o[4] = (short)f16_rne(bb.x); o[5] = (short)f16_rne(bb.y);
    o[6] = (short)f16_rne(bb.z); o[7] = (short)f16_rne(bb.w);
    *(short8*)(xt + (size_t)j * 8) = o;
}

// ---------------- conv1: f16 MFMA, 256t x 64h, B-in-LDS, 3 blocks/CU, XCD swizzle ----------------
// r10 configuration, unchanged: measured 108.5us, MfmaUtil 50%, FETCH 38MB.
// At its LDS+barrier floor (LDS reads ~57us + conflicts ~27us + DMA ~14us vs MFMA 58us).
__device__ __forceinline__ void c1_stageA(const unsigned short* xt, const unsigned short* zerobuf,
                                          half8* Ab, int b, int t0, int cc, int lane, int wid)
{
    #pragma unroll
    for (int part = 0; part < 5; ++part) {
        int row = part * 64 + lane;
        int t = t0 + row - 3;
        const unsigned short* src = zerobuf;
        if (row < 262 && t >= 0 && t < T) {
            int grp = t >> 8, rin = t & 255;
            src = xt + ((size_t)((((b * 32 + grp) * 8 + cc) * 4 + wid) * 256 + rin)) * 8;
        }
        gl_lds16(src, &Ab[wid * 322 + part * 64]);
    }
}
__device__ __forceinline__ void c1_stageB(const unsigned short* WbL, half8* Bb,
                                          int hcc, int lane, int wid)
{
    #pragma unroll
    for (int s = 0; s < 7; ++s) {
        int slot = wid * 7 + s;
        const unsigned short* src = WbL + ((size_t)(hcc * 28 + slot)) * 512 + lane * 8;
        gl_lds16(src, &Bb[slot * 66]);
    }
}

__global__ __launch_bounds__(256, 3) void conv1_mfma(
    const unsigned short* __restrict__ xt,
    const unsigned short* __restrict__ WbL,
    const float* __restrict__ b1,
    const unsigned short* __restrict__ zerobuf,
    unsigned short* __restrict__ h1t)
{
    __shared__ half8 A8[4 * 322];        // [q][row], rows 0..261 valid (t = t0+row-3)  20.6 KB
    __shared__ half8 B8[28 * 66];        // [kw*4+bq][h]                                29.6 KB
    const int tid = threadIdx.x, lane = tid & 63, wid = tid >> 6;
    // XCD-aware bijective swizzle (2048 % 8 == 0); ycol fastest -> 4 y-siblings of an
    // xt panel share one XCD's L2 (measured FETCH 135->38MB).
    const int bid = blockIdx.x;
    const int cid = (bid & 7) * 256 + (bid >> 3);
    const int xcol = cid >> 2;           // 0..511 = b*32+grp
    const int ycol = cid & 3;            // h-group
    const int b  = xcol >> 5;
    const int grp = xcol & 31;
    const int t0 = grp << 8;
    const int h0 = ycol << 6;
    const int q = lane >> 4, l15 = lane & 15;

    f32x4 acc[4][4] = {};

    for (int cc = 0; cc < 8; ++cc) {
        __syncthreads();                 // previous compute fully consumed LDS
        c1_stageA(xt, zerobuf, A8, b, t0, cc, lane, wid);
        c1_stageB(WbL, B8, ycol * 8 + cc, lane, wid);
        __syncthreads();                 // drain DMAs
        #pragma unroll
        for (int kw = 0; kw < 7; ++kw) {
            half8 ah[4], bh[4];
            const int rbase = wid * 64 + l15 + kw;
            #pragma unroll
            for (int i = 0; i < 4; ++i) ah[i] = A8[q * 322 + rbase + i * 16];
            #pragma unroll
            for (int j = 0; j < 4; ++j) bh[j] = B8[(kw * 4 + q) * 66 + j * 16 + l15];
            #pragma unroll
            for (int i = 0; i < 4; ++i)
                #pragma unroll
                for (int j = 0; j < 4; ++j)
                    acc[i][j] = __builtin_amdgcn_mfma_f32_16x16x32_f16(ah[i], bh[j], acc[i][j], 0, 0, 0);
        }
    }
    // epilogue: bias+relu, store h1 f16 in the tiled layout
    #pragma unroll
    for (int j = 0; j < 4; ++j) {
        int h = h0 + j * 16 + l15;
        float bb = b1[h];
        int hcc = h >> 5, hwid = (h >> 3) & 3, he = h & 7;
        size_t hbase = ((size_t)(((b * 32 + grp) * 8 + hcc) * 4 + hwid)) * 2048 + he;
        #pragma unroll
        for (int i = 0; i < 4; ++i) {
            int rb = wid * 64 + i * 16 + q * 4;    // rin
            #pragma unroll
            for (int r = 0; r < 4; ++r)
                h1t[hbase + (size_t)(rb + r) * 8] = f16_rne(fmaxf(acc[i][j][r] + bb, 0.f));
        }
    }
}

// ---------------- conv2: f16 MFMA + fused 1x1 score, 256t x 128h, 2 blocks/CU ----------------
// REVERTED to the r7 geometry + XCD swizzle. Ledger evidence (r7->r8): conv2 at 64h/3-per-CU
// cost ~17us vs 128h/2-per-CU -- conv2 has only 3 kw of MFMA per staging phase, so the
// bigger tile (2x fewer blocks -> 2x fewer barrier/stage events, 2x fewer h1t reads) wins.
__device__ __forceinline__ void c2_stageA(const unsigned short* ht, const unsigned short* zerobuf,
                                          half8* Ab, int b, int t0, int cc, int lane, int wid)
{
    #pragma unroll
    for (int part = 0; part < 5; ++part) {
        int row = part * 64 + lane;
        int t = t0 + row - 1;
        const unsigned short* src = zerobuf;
        if (row < 258 && t >= 0 && t < T) {
            int grp = t >> 8, rin = t & 255;
            src = ht + ((size_t)((((b * 32 + grp) * 8 + cc) * 4 + wid) * 256 + rin)) * 8;
        }
        gl_lds16(src, &Ab[wid * 322 + part * 64]);
    }
}
__device__ __forceinline__ void c2_stageB(const unsigned short* WbL, half8* Bb,
                                          int hcc, int lane, int wid)
{
    #pragma unroll
    for (int s = 0; s < 6; ++s) {
        int bs = wid * 6 + s;
        int slot = bs >> 1, half = bs & 1;
        const unsigned short* src = WbL + ((size_t)((hcc * 12 + slot) * 2 + half)) * 512 + lane * 8;
        gl_lds16(src, &Bb[slot * 130 + half * 64]);
    }
}

__global__ __launch_bounds__(256, 2) void conv2_mfma(
    const unsigned short* __restrict__ h1t,
    const unsigned short* __restrict__ WbL,
    const float* __restrict__ b2, const float* __restrict__ v,
    const unsigned short* __restrict__ zerobuf,
    float* __restrict__ dlog)
{
    __shared__ half8 A8[4 * 322];        // rows 0..257 valid (t = t0+row-1)   20.6 KB
    __shared__ half8 B8[12 * 130];       // 3 kw x 4 bq x [half*64+h]          24.9 KB
    const int tid = threadIdx.x, lane = tid & 63, wid = tid >> 6;
    // XCD-aware bijective swizzle over 1024 blocks (1024 % 8 == 0); ycol fastest.
    const int bid = blockIdx.x;
    const int cid = (bid & 7) * 128 + (bid >> 3);
    const int xcol = cid >> 1;           // 0..511 = b*32+grp
    const int ycol = cid & 1;            // h-group (2 x 128h)
    const int b  = xcol >> 5;
    const int t0 = (xcol & 31) << 8;
    const int h0 = ycol << 7;
    const int q = lane >> 4, l15 = lane & 15;

    f32x4 acc[4][8] = {};

    for (int cc = 0; cc < 8; ++cc) {
        __syncthreads();
        c2_stageA(h1t, zerobuf, A8, b, t0, cc, lane, wid);
        c2_stageB(WbL, B8, ycol * 8 + cc, lane, wid);
        __syncthreads();
        #pragma unroll
        for (int kw = 0; kw < 3; ++kw) {
            half8 ah[4], bh[8];
            const int rbase = wid * 64 + l15 + kw;
            #pragma unroll
            for (int i = 0; i < 4; ++i) ah[i] = A8[q * 322 + rbase + i * 16];
            #pragma unroll
            for (int j = 0; j < 8; ++j) bh[j] = B8[(kw * 4 + q) * 130 + j * 16 + l15];
            #pragma unroll
            for (int i = 0; i < 4; ++i)
                #pragma unroll
                for (int j = 0; j < 8; ++j)
                    acc[i][j] = __builtin_amdgcn_mfma_f32_16x16x32_f16(ah[i], bh[j], acc[i][j], 0, 0, 0);
        }
    }
    // epilogue: p = sum_h v[h]*relu(h2+b2), reduce 16 lanes per quad, atomicAdd per token
    float vv[8], bb[8];
    #pragma unroll
    for (int j = 0; j < 8; ++j) {
        int h = h0 + j * 16 + l15;
        vv[j] = v[h]; bb[j] = b2[h];
    }
    #pragma unroll
    for (int i = 0; i < 4; ++i) {
        int tb = t0 + wid * 64 + i * 16 + q * 4;
        #pragma unroll
        for (int r = 0; r < 4; ++r) {
            float s = 0.f;
            #pragma unroll
            for (int j = 0; j < 8; ++j)
                s += fmaxf(acc[i][j][r] + bb[j], 0.f) * vv[j];
            #pragma unroll
            for (int m = 1; m < 16; m <<= 1)
                s += __shfl_xor(s, m, 64);
            if (l15 == 0) atomicAdd(&dlog[b * T + tb + r], s);
        }
    }
}

// ---------------- boundary bit + uncertainty list ----------------
__global__ void boundary_kernel(const float* __restrict__ d, const int* __restrict__ padmask,
                                const float* __restrict__ b3,
                                int* __restrict__ isb, int* __restrict__ ucount,
                                int* __restrict__ ulist)
{
    int bt = blockIdx.x * 256 + threadIdx.x;
    if (bt >= BT) return;
    int pad = padmask[bt];
    float dd = d[bt] + (b3[1] - b3[0]);
    isb[bt] = (pad == 0 && dd > 0.f) ? 1 : 0;
    if (pad == 0 && fabsf(dd) < TAU) {
        int slot = atomicAdd(ucount, 1);
        if (slot < RCAP) ulist[slot] = bt;
    }
}

// ---------------- recheck phase 1: conv1 in f64, 4 blocks/candidate ----------------
__global__ __launch_bounds__(256) void recheck_h1(
    const float* __restrict__ x, const float* __restrict__ W1R,
    const float* __restrict__ b1, const float* __restrict__ zerof,
    const int* __restrict__ ulist, const int* __restrict__ ucount,
    float* __restrict__ h1f)
{
    __shared__ float xs[9 * CDIM];       // x[t-4..t+4][:], zero OOB rows
    int n = *ucount; if (n > RCAP) n = RCAP;
    const int tid = threadIdx.x, lane = tid & 63, wid = tid >> 6;
    const int g = tid >> 4, l = tid & 15;
    const int nit = 4 * n;
    for (int item = blockIdx.x; item < nit; item += gridDim.x) {
        const int li = item >> 2, hc = item & 3;
        const int bt = ulist[li];
        const int b = bt >> 13, t = bt & (T - 1);
        __syncthreads();                 // xs from previous item fully consumed
        for (int r = wid; r < 9; r += 4) {
            int tt = t + r - 4;
            const float* src = (tt >= 0 && tt < T)
                ? x + (size_t)(b * T + tt) * CDIM + lane * 4 : zerof;
            gl_lds16(src, &xs[r * CDIM]);
        }
        __syncthreads();
        #pragma unroll
        for (int s = 0; s < 4; ++s) {
            const int h = hc * 64 + s * 16 + g;
            const float* wr = &W1R[(size_t)h * 1792];
            double p0 = 0.0, p1 = 0.0, p2 = 0.0;
            #pragma unroll 7
            for (int it = 0; it < 28; ++it) {
                const int e = it * 64 + l * 4;
                float4 w4 = *(const float4*)&wr[e];
                double w0 = (double)w4.x, w1v = (double)w4.y,
                       w2v = (double)w4.z, w3v = (double)w4.w;
                const float* x0 = &xs[e];
                p0 += w0 * (double)x0[0] + w1v * (double)x0[1]
                    + w2v * (double)x0[2] + w3v * (double)x0[3];
                const float* x1 = &xs[256 + e];
                p1 += w0 * (double)x1[0] + w1v * (double)x1[1]
                    + w2v * (double)x1[2] + w3v * (double)x1[3];
                const float* x2 = &xs[512 + e];
                p2 += w0 * (double)x2[0] + w1v * (double)x2[1]
                    + w2v * (double)x2[2] + w3v * (double)x2[3];
            }
            #pragma unroll
            for (int m = 1; m < 16; m <<= 1) {
                p0 += __shfl_xor(p0, m);
                p1 += __shfl_xor(p1, m);
                p2 += __shfl_xor(p2, m);
            }
            if (l == 0) {
                double bb = (double)b1[h];
                double a0 = bb + p0, a1 = bb + p1, a2 = bb + p2;
                float* o = &h1f[(size_t)li * 768];
                o[0 * 256 + h] = (t - 1 >= 0 && a0 > 0.0) ? (float)a0 : 0.f;
                o[1 * 256 + h] = (a1 > 0.0) ? (float)a1 : 0.f;
                o[2 * 256 + h] = (t + 1 < T && a2 > 0.0) ? (float)a2 : 0.f;
            }
        }
    }
}

// ---------------- recheck phase 2: conv2 + 1x1 in f64, 4 blocks/candidate ----------------
__global__ __launch_bounds__(256) void recheck_h2(
    const float* __restrict__ h1f, const float* __restrict__ W2R,
    const float* __restrict__ b2, const float* __restrict__ w3,
    const int* __restrict__ ulist, const int* __restrict__ ucount,
    double* __restrict__ dsum)
{
    __shared__ float hs[768];
    __shared__ double red[64];
    int n = *ucount; if (n > RCAP) n = RCAP;
    const int tid = threadIdx.x, lane = tid & 63, wid = tid >> 6;
    const int g = tid >> 4, l = tid & 15;
    const int nit = 4 * n;
    for (int item = blockIdx.x; item < nit; item += gridDim.x) {
        const int li = item >> 2, hc = item & 3;
        __syncthreads();                 // hs/red from previous item consumed
        if (wid < 3)
            gl_lds16(h1f + (size_t)li * 768 + wid * 256 + lane * 4, &hs[wid * 256]);
        __syncthreads();
        #pragma unroll
        for (int s = 0; s < 4; ++s) {
            const int h = hc * 64 + s * 16 + g;
            const float* wr = &W2R[(size_t)h * 768];
            double c0 = 0.0;
            #pragma unroll
            for (int it = 0; it < 12; ++it) {
                const int e = it * 64 + l * 4;
                float4 w4 = *(const float4*)&wr[e];
                const float* hv = &hs[e];
                c0 += (double)w4.x * (double)hv[0] + (double)w4.y * (double)hv[1]
                    + (double)w4.z * (double)hv[2] + (double)w4.w * (double)hv[3];
            }
            #pragma unroll
            for (int m = 1; m < 16; m <<= 1) c0 += __shfl_xor(c0, m);
            if (l == 0) {
                double acc2 = (double)b2[h] + c0;
                double h2v = acc2 > 0.0 ? acc2 : 0.0;
                double vd = (double)w3[HDIM + h] - (double)w3[h];
                red[s * 16 + g] = vd * h2v;
            }
        }
        __syncthreads();
        if (tid < 32) red[tid] += red[tid + 32];
        __syncthreads();
        if (tid < 16) red[tid] += red[tid + 16];
        __syncthreads();
        if (tid == 0) {
            double ssum = 0.0;
            #pragma unroll
            for (int i = 0; i < 16; ++i) ssum += red[i];
            atomicAdd(&dsum[li], ssum);
        }
    }
}

// ---------------- recheck finalize ----------------
__global__ void recheck_final(const double* __restrict__ dsum, const float* __restrict__ b3,
                              const int* __restrict__ ulist, const int* __restrict__ ucount,
                              int* __restrict__ isb)
{
    int n = *ucount; if (n > RCAP) n = RCAP;
    int li = blockIdx.x * 256 + threadIdx.x;
    if (li >= n) return;
    double dd = dsum[li] + ((double)b3[1] - (double)b3[0]);
    isb[ulist[li]] = (dd > 0.0) ? 1 : 0;
}

// ---------------- per-batch inclusive cumsum -> seg_id, n_valid ----------------
__global__ __launch_bounds__(1024) void scan_kernel(
    const int* __restrict__ isb, const int* __restrict__ padmask,
    int* __restrict__ sid, int* __restrict__ nvalid)
{
    __shared__ int ssum[1024];
    const int b = blockIdx.x, tid = threadIdx.x;
    const int base = b * T;
    int vals[8]; int s = 0;
    #pragma unroll
    for (int i = 0; i < 8; ++i) { vals[i] = isb[base + tid * 8 + i]; s += vals[i]; }
    ssum[tid] = s;
    __syncthreads();
    for (int off = 1; off < 1024; off <<= 1) {
        int add = (tid >= off) ? ssum[tid - off] : 0;
        __syncthreads();
        ssum[tid] += add;
        __syncthreads();
    }
    int run = ssum[tid] - s;
    #pragma unroll
    for (int i = 0; i < 8; ++i) {
        int t = tid * 8 + i;
        run += vals[i];
        sid[base + t] = (padmask[base + t] != 0) ? T : run;
    }
    if (tid == 1023) {
        int nb = ssum[1023];
        nvalid[b] = (padmask[base] == 0) ? (nb + 1) : 0;
    }
}

// ---------------- segment range extraction ----------------
__global__ void segbounds_kernel(const int* __restrict__ sid, const int* __restrict__ padmask,
                                 int* __restrict__ sst, int* __restrict__ sen)
{
    int bt = blockIdx.x * 256 + threadIdx.x;
    if (bt >= BT) return;
    if (padmask[bt] != 0) return;
    int t = bt & (T - 1);
    int b = bt >> 13;
    int s = sid[bt];
    if (t == 0) {
        if (s < T) sst[b * T + s] = 0;
    } else if (s != sid[bt - 1]) {
        if (s < T) sst[b * T + s] = t;
    }
    bool last = (t == T - 1) || (padmask[bt + 1] != 0);
    if (s < T && (last || sid[bt + 1] != s)) sen[b * T + s] = t + 1;
}

// ---------------- segment-mean pooling + new_pad ----------------
__global__ __launch_bounds__(256) void pool_kernel(
    const float* __restrict__ x, const int* __restrict__ sst,
    const int* __restrict__ sen, const int* __restrict__ nvalid,
    float* __restrict__ out)
{
    int slot = blockIdx.x * 4 + (threadIdx.x >> 6);
    int lane = threadIdx.x & 63;
    int b = slot >> 13;
    int s = slot & (T - 1);
    int nv = nvalid[b];
    float4 res = make_float4(0.f, 0.f, 0.f, 0.f);
    if (s < nv) {
        int st = sst[slot], en = sen[slot];
        if (st >= 0 && en > st) {
            float4 a = make_float4(0.f, 0.f, 0.f, 0.f);
            const float* xp = &x[(size_t)(b * T + st) * CDIM + lane * 4];
            for (int t = st; t < en; ++t) {
                float4 xv = *(const float4*)xp;
                a.x += xv.x; a.y += xv.y; a.z += xv.z; a.w += xv.w;
                xp += CDIM;
            }
            float inv = 1.f / (float)(en - st);
            res = make_float4(a.x * inv, a.y * inv, a.z * inv, a.w * inv);
        }
    }
    *(float4*)&out[(size_t)slot * CDIM + lane * 4] = res;
    if (lane == 0) out[(size_t)BT * CDIM + slot] = (s < nv) ? 0.f : 1.f;
}

extern "C" void kernel_launch(void* const* d_in, const int* in_sizes, int n_in,
                              void* d_out, int out_size, void* d_ws, size_t ws_size,
                              hipStream_t stream)
{
    const float* x  = (const float*)d_in[0];
    const int* padmask = (const int*)d_in[1];
    const float* w1 = (const float*)d_in[2];
    const float* b1 = (const float*)d_in[3];
    const float* w2 = (const float*)d_in[4];
    const float* b2 = (const float*)d_in[5];
    const float* w3 = (const float*)d_in[6];
    const float* b3 = (const float*)d_in[7];

    char* ws = (char*)d_ws;
    float* W1R = (float*)(ws + B_W1T);
    float* W2R = (float*)(ws + B_W2T);
    float* v   = (float*)(ws + B_V);
    float* dlog = (float*)(ws + B_D);
    int* isb = (int*)(ws + B_ISB);
    int* sid = (int*)(ws + B_SID);
    int* sst = (int*)(ws + B_SST);
    int* sen = (int*)(ws + B_SEN);
    int* nv  = (int*)(ws + B_NV);
    int* uct = (int*)(ws + B_UCT);
    int* ul  = (int*)(ws + B_UL);
    unsigned short* zerobuf = (unsigned short*)(ws + B_ZERO);
    unsigned short* W1bL = (unsigned short*)(ws + B_W1B);
    unsigned short* W2bL = (unsigned short*)(ws + B_W2B);
    float* h1f = (float*)(ws + B_H1F);
    double* dsum = (double*)(ws + B_DSUM);

    float* out = (float*)d_out;
    // d_out scratch: h1t f16 tiled [BT][256] in the first half, xt f16 tiled in the second
    unsigned short* h1t = (unsigned short*)out;
    unsigned short* xt  = h1t + (size_t)BT * 256;

    hipMemsetAsync(dlog, 0, BT * sizeof(float), stream);
    hipMemsetAsync(sst, 0xFF, BT * sizeof(int), stream);
    hipMemsetAsync(sen, 0xFF, BT * sizeof(int), stream);
    hipMemsetAsync(uct, 0, sizeof(int), stream);
    hipMemsetAsync(zerobuf, 0, 256, stream);
    hipMemsetAsync(dsum, 0, RCAP * sizeof(double), stream);

    repack_kernel<<<1024, 256, 0, stream>>>(w1, w2, w3, W1R, W2R, v, W1bL, W2bL);
    xcast_kernel<<<BT * 256 / (8 * 256), 256, 0, stream>>>(x, xt);
    conv1_mfma<<<2048, 256, 0, stream>>>(xt, W1bL, b1, zerobuf, h1t);
    conv2_mfma<<<1024, 256, 0, stream>>>(h1t, W2bL, b2, v, zerobuf, dlog);
    boundary_kernel<<<BT / 256, 256, 0, stream>>>(dlog, padmask, b3, isb, uct, ul);
    recheck_h1<<<4096, 256, 0, stream>>>(x, W1R, b1, (const float*)zerobuf, ul, uct, h1f);
    recheck_h2<<<4096, 256, 0, stream>>>(h1f, W2R, b2, w3, ul, uct, dsum);
    recheck_final<<<RCAP / 256, 256, 0, stream>>>(dsum, b3, ul, uct, isb);
    scan_kernel<<<BSZ, 1024, 0, stream>>>(isb, padmask, sid, nv);
    segbounds_kernel<<<BT / 256, 256, 0, stream>>>(sid, padmask, sst, sen);
    pool_kernel<<<BT / 4, 256, 0, stream>>>(x, sst, sen, nv, out);
}